// Round 4
// baseline (293.535 us; speedup 1.0000x reference)
//
#include <hip/hip_runtime.h>
#include <hip/hip_bf16.h>

#define T_TOK 8192
#define DDIM  1024
#define NEXP  8
#define NT    16   // K-tiles of 64

typedef __attribute__((ext_vector_type(8))) short bf16x8;
typedef __attribute__((ext_vector_type(4))) float f32x4;

__device__ inline unsigned short f2bf(float f) {
  union { float f; unsigned int u; } a; a.f = f;
  unsigned int u = a.u;
  unsigned int r = (u + 0x7fffu + ((u >> 16) & 1u)) >> 16;  // RNE
  return (unsigned short)r;
}

__device__ inline float bf2f(unsigned short u) {
  union { unsigned int u; float f; } a; a.u = ((unsigned int)u) << 16;
  return a.f;
}

__device__ inline void gload_lds16(const void* g, void* l) {
  __builtin_amdgcn_global_load_lds(
      (const __attribute__((address_space(1))) void*)g,
      (__attribute__((address_space(3))) void*)l, 16, 0, 0);
}

// ---------------- cast f32 -> bf16 (expert weights) ----------------
__global__ __launch_bounds__(256) void cast_bf16_kernel(
    const float* __restrict__ in, unsigned short* __restrict__ out, int n4) {
  int i = blockIdx.x * 256 + threadIdx.x;
  if (i >= n4) return;
  float4 v = reinterpret_cast<const float4*>(in)[i];
  ushort4 o;
  o.x = f2bf(v.x); o.y = f2bf(v.y); o.z = f2bf(v.z); o.w = f2bf(v.w);
  reinterpret_cast<ushort4*>(out)[i] = o;
}

// ---------------- gating (fused x->bf16 cast), NO global atomics ----------------
__global__ __launch_bounds__(256) void gate_kernel(
    const float* __restrict__ x, const float* __restrict__ gw,
    unsigned short* __restrict__ xb,
    int* __restrict__ e_of, float* __restrict__ w_of) {
  int t = blockIdx.x * 4 + (threadIdx.x >> 6);
  int lane = threadIdx.x & 63;
  const float4* xr = reinterpret_cast<const float4*>(x + (size_t)t * DDIM);
  ushort4* xbr = reinterpret_cast<ushort4*>(xb + (size_t)t * DDIM);
  float acc[NEXP];
#pragma unroll
  for (int e = 0; e < NEXP; ++e) acc[e] = 0.f;
#pragma unroll
  for (int c = 0; c < 4; ++c) {
    float4 xv = xr[c * 64 + lane];
    ushort4 o;
    o.x = f2bf(xv.x); o.y = f2bf(xv.y); o.z = f2bf(xv.z); o.w = f2bf(xv.w);
    xbr[c * 64 + lane] = o;
#pragma unroll
    for (int e = 0; e < NEXP; ++e) {
      float4 g = reinterpret_cast<const float4*>(gw + e * DDIM)[c * 64 + lane];
      acc[e] += xv.x * g.x + xv.y * g.y + xv.z * g.z + xv.w * g.w;
    }
  }
#pragma unroll
  for (int e = 0; e < NEXP; ++e) {
#pragma unroll
    for (int s = 32; s > 0; s >>= 1) acc[e] += __shfl_xor(acc[e], s);
  }
  if (lane == 0) {
    int e0 = 0; float v0 = acc[0];
#pragma unroll
    for (int e = 1; e < NEXP; ++e) if (acc[e] > v0) { v0 = acc[e]; e0 = e; }
    int e1 = (e0 == 0) ? 1 : 0; float v1 = acc[e1];
#pragma unroll
    for (int e = 0; e < NEXP; ++e)
      if (e != e0 && acc[e] > v1) { v1 = acc[e]; e1 = e; }
    float w1 = 1.f / (1.f + expf(v0 - v1));
    float w0 = 1.f - w1;
    e_of[2 * t] = e0; e_of[2 * t + 1] = e1;
    w_of[2 * t] = w0; w_of[2 * t + 1] = w1;
  }
}

// ---------------- counts: LDS histogram, 8 global atomics per block ----------------
__global__ __launch_bounds__(512) void count_kernel(
    const int* __restrict__ e_of, int* __restrict__ counts) {
  __shared__ int lc[NEXP];
  int tid = threadIdx.x;
  if (tid < NEXP) lc[tid] = 0;
  __syncthreads();
  atomicAdd(&lc[e_of[blockIdx.x * 512 + tid]], 1);
  __syncthreads();
  if (tid < NEXP) atomicAdd(&counts[tid], lc[tid]);
}

// ---------------- scan + block map ----------------
__global__ void scan_kernel(const int* __restrict__ counts,
                            int* __restrict__ offs, int* __restrict__ cursor,
                            int* __restrict__ nblk, int* __restrict__ blkmap) {
  if (threadIdx.x == 0) {
    int s = 0;
    for (int e = 0; e < NEXP; ++e) { offs[e] = s; cursor[e] = s; s += counts[e]; }
    int nb = 0;
    for (int e = 0; e < NEXP; ++e) {
      int mb = (counts[e] + 255) >> 8;
      for (int j = 0; j < mb; ++j) blkmap[nb++] = (e << 8) | j;
    }
    nblk[0] = nb;
  }
}

// ---------------- build row lists: block-aggregated cursor atomics ----------------
__global__ __launch_bounds__(256) void build_kernel(
    const int* __restrict__ e_of, int* __restrict__ cursor,
    int* __restrict__ row_src, int* __restrict__ tok_row) {
  __shared__ int lc[NEXP];
  __shared__ int lbase[NEXP];
  int tid = threadIdx.x;
  if (tid < NEXP) lc[tid] = 0;
  __syncthreads();
  int i0 = blockIdx.x * 512 + tid;
  int i1 = i0 + 256;
  int ea = e_of[i0], eb = e_of[i1];
  int ra = atomicAdd(&lc[ea], 1);
  int rb = atomicAdd(&lc[eb], 1);
  __syncthreads();
  if (tid < NEXP) lbase[tid] = atomicAdd(&cursor[tid], lc[tid]);
  __syncthreads();
  int pa = lbase[ea] + ra;
  int pb = lbase[eb] + rb;
  row_src[pa] = i0 >> 1;
  tok_row[i0] = pa;
  row_src[pb] = i1 >> 1;
  tok_row[i1] = pb;
}

// ---------------- grouped GEMM: 256x256, BK=64, 8 waves, counted-vmcnt pipeline ----
// LDS swizzle: logical (row, k) -> short index row*64 + (((k>>3) ^ (row&7))<<3) + (k&7)
// Staged via linear global_load_lds dest + inverse-permuted per-lane global source.
// Sync: raw s_barrier + s_waitcnt vmcnt(8) — tile t+1's 8 loads stay in flight
// across barriers; vmcnt(0) only at the peeled final tile.
__global__ __launch_bounds__(512, 2) void gemm_kernel(
    const unsigned short* __restrict__ xb, const unsigned short* __restrict__ Wb,
    const int* __restrict__ row_src, const int* __restrict__ counts,
    const int* __restrict__ offs, const int* __restrict__ nblk,
    const int* __restrict__ blkmap, unsigned short* __restrict__ Yb) {
  // bijective XCD swizzle over nwg=284 (q=35, r=4)
  int orig = blockIdx.x;
  int xcd = orig & 7;
  int idx = orig >> 3;
  int wg = (xcd < 4 ? xcd * 36 : 144 + (xcd - 4) * 35) + idx;
  int mi = wg >> 2, ni = wg & 3;
  if (mi >= nblk[0]) return;
  int em = blkmap[mi];
  int e = em >> 8, mj = em & 255;
  int ce = counts[e];
  int base = offs[e];
  int m0 = mj << 8;
  int n0 = ni << 8;

  __shared__ unsigned short As[2][256 * 64];  // 64 KB
  __shared__ unsigned short Bs[2][256 * 64];  // 64 KB

  int tid = threadIdx.x;
  int lane = tid & 63;
  int wid = tid >> 6;          // 0..7
  int wr = wid >> 2, wc = wid & 3;

  // staging: wave wid owns chunks g = wid*4+j (8 rows each) for A and B
  int rl = lane >> 3, sl = lane & 7;
  int cperm = (sl ^ rl) * 8;   // pre-swizzled global element offset
  const unsigned short* We = Wb + (size_t)e * DDIM * DDIM;
  const unsigned short* asrc[4];
  const unsigned short* bsrc[4];
#pragma unroll
  for (int j = 0; j < 4; ++j) {
    int g = wid * 4 + j;
    int row = g * 8 + rl;            // [0,256)
    int i = m0 + row; if (i > ce - 1) i = ce - 1;
    int tk = row_src[base + i];
    asrc[j] = xb + (size_t)tk * DDIM + cperm;
    bsrc[j] = We + (size_t)(n0 + row) * DDIM + cperm;
  }

  f32x4 acc[8][4];
#pragma unroll
  for (int m = 0; m < 8; ++m)
#pragma unroll
    for (int n = 0; n < 4; ++n) acc[m][n] = (f32x4){0.f, 0.f, 0.f, 0.f};

  int frow_a = wr * 128 + (lane & 15);
  int frow_b = wc * 64 + (lane & 15);
  int fchunk = lane >> 4;            // 0..3

#define STAGE(buf, koff)                                                \
  {                                                                     \
    _Pragma("unroll") for (int j = 0; j < 4; ++j)                       \
        gload_lds16(asrc[j] + (koff), &As[buf][(wid * 4 + j) * 512]);   \
    _Pragma("unroll") for (int j = 0; j < 4; ++j)                       \
        gload_lds16(bsrc[j] + (koff), &Bs[buf][(wid * 4 + j) * 512]);   \
  }

// one phase: m-half mh, k-step ks; B-frags (re)loaded when RB
#define PHASE(bb, ks, mh, RB)                                           \
  {                                                                     \
    int c = fchunk + (ks) * 4;                                          \
    bf16x8 af[4];                                                       \
    _Pragma("unroll") for (int m = 0; m < 4; ++m) {                     \
      int row = frow_a + (mh) * 64 + m * 16;                            \
      af[m] = *reinterpret_cast<const bf16x8*>(                         \
          &As[bb][row * 64 + ((c ^ (row & 7)) << 3)]);                  \
    }                                                                   \
    if (RB) {                                                           \
      _Pragma("unroll") for (int n = 0; n < 4; ++n) {                   \
        int row = frow_b + n * 16;                                      \
        bfr[n] = *reinterpret_cast<const bf16x8*>(                      \
            &Bs[bb][row * 64 + ((c ^ (row & 7)) << 3)]);                \
      }                                                                 \
    }                                                                   \
    __builtin_amdgcn_s_setprio(1);                                      \
    _Pragma("unroll") for (int m = 0; m < 4; ++m)                       \
        _Pragma("unroll") for (int n = 0; n < 4; ++n)                   \
            acc[(mh) * 4 + m][n] = __builtin_amdgcn_mfma_f32_16x16x32_bf16( \
                af[m], bfr[n], acc[(mh) * 4 + m][n], 0, 0, 0);          \
    __builtin_amdgcn_s_setprio(0);                                      \
  }

#define COMPUTE(bb)                                                     \
  {                                                                     \
    bf16x8 bfr[4];                                                      \
    PHASE(bb, 0, 0, 1)                                                  \
    PHASE(bb, 0, 1, 0)                                                  \
    PHASE(bb, 1, 0, 1)                                                  \
    PHASE(bb, 1, 1, 0)                                                  \
  }

  // prologue: stage tiles 0 and 1
  STAGE(0, 0)
  STAGE(1, 64)

  for (int t = 0; t < NT - 1; ++t) {
    int b = t & 1;
    asm volatile("s_waitcnt vmcnt(8)" ::: "memory");  // tile t landed; t+1 in flight
    __builtin_amdgcn_s_barrier();
    asm volatile("" ::: "memory");
    if (b == 0) { COMPUTE(0) } else { COMPUTE(1) }
    asm volatile("" ::: "memory");
    __builtin_amdgcn_s_barrier();                      // all waves done reading buf b
    asm volatile("" ::: "memory");
    if (t + 2 < NT) {
      int koff = (t + 2) * 64;
      if (b == 0) STAGE(0, koff) else STAGE(1, koff)
    }
  }
  asm volatile("s_waitcnt vmcnt(0)" ::: "memory");     // epilogue drain
  __builtin_amdgcn_s_barrier();
  asm volatile("" ::: "memory");
  COMPUTE(1)

#undef COMPUTE
#undef PHASE
#undef STAGE

  // epilogue: C/D layout col=lane&15, row=(lane>>4)*4+reg
  int crow = (lane >> 4) * 4;
  int ccol = lane & 15;
#pragma unroll
  for (int m = 0; m < 8; ++m) {
#pragma unroll
    for (int r = 0; r < 4; ++r) {
      int grow = m0 + wr * 128 + m * 16 + crow + r;
      if (grow < ce) {
        unsigned short* yr = Yb + (size_t)(base + grow) * DDIM + n0 + wc * 64 + ccol;
#pragma unroll
        for (int n = 0; n < 4; ++n)
          yr[n * 16] = f2bf(acc[m][n][r]);
      }
    }
  }
}

// ---------------- combine: out[t] = w0*Y[p0] + w1*Y[p1] ----------------
__global__ __launch_bounds__(256) void combine_kernel(
    const unsigned short* __restrict__ Yb, const int* __restrict__ tok_row,
    const float* __restrict__ w_of, float* __restrict__ out) {
  int t = blockIdx.x;
  int d = threadIdx.x * 4;
  int p0 = tok_row[2 * t], p1 = tok_row[2 * t + 1];
  float w0 = w_of[2 * t], w1 = w_of[2 * t + 1];
  ushort4 y0 = reinterpret_cast<const ushort4*>(Yb + (size_t)p0 * DDIM + d)[0];
  ushort4 y1 = reinterpret_cast<const ushort4*>(Yb + (size_t)p1 * DDIM + d)[0];
  float4 o;
  o.x = w0 * bf2f(y0.x) + w1 * bf2f(y1.x);
  o.y = w0 * bf2f(y0.y) + w1 * bf2f(y1.y);
  o.z = w0 * bf2f(y0.z) + w1 * bf2f(y1.z);
  o.w = w0 * bf2f(y0.w) + w1 * bf2f(y1.w);
  reinterpret_cast<float4*>(out + (size_t)t * DDIM + d)[0] = o;
}

extern "C" void kernel_launch(void* const* d_in, const int* in_sizes, int n_in,
                              void* d_out, int out_size, void* d_ws, size_t ws_size,
                              hipStream_t stream) {
  const float* x  = (const float*)d_in[0];
  const float* gw = (const float*)d_in[1];
  const float* ew = (const float*)d_in[2];
  float* out = (float*)d_out;
  char* ws = (char*)d_ws;

  unsigned short* xb = (unsigned short*)(ws);                    // 16 MB
  unsigned short* Wb = (unsigned short*)(ws + 16777216);         // 16 MB
  unsigned short* Yb = (unsigned short*)(ws + 33554432);         // 32 MB
  int*   e_of    = (int*)  (ws + 67108864);
  float* w_of    = (float*)(ws + 67174400);
  int*   row_src = (int*)  (ws + 67239936);
  int*   tok_row = (int*)  (ws + 67305472);
  int*   counts  = (int*)  (ws + 67371008);
  int*   offs    = (int*)  (ws + 67371040);
  int*   cursor  = (int*)  (ws + 67371072);
  int*   nblk    = (int*)  (ws + 67371104);
  int*   blkmap  = (int*)  (ws + 67371136);

  hipMemsetAsync(counts, 0, 32, stream);

  int n4w = (NEXP * DDIM * DDIM) / 4;
  cast_bf16_kernel<<<n4w / 256, 256, 0, stream>>>(ew, Wb, n4w);

  gate_kernel<<<T_TOK / 4, 256, 0, stream>>>(x, gw, xb, e_of, w_of);
  count_kernel<<<32, 512, 0, stream>>>(e_of, counts);
  scan_kernel<<<1, 64, 0, stream>>>(counts, offs, cursor, nblk, blkmap);
  build_kernel<<<32, 256, 0, stream>>>(e_of, cursor, row_src, tok_row);

  gemm_kernel<<<284, 512, 0, stream>>>(xb, Wb, row_src, counts, offs, nblk, blkmap, Yb);

  combine_kernel<<<T_TOK, 256, 0, stream>>>(Yb, tok_row, w_of, out);
}

// Round 5
// 118.284 us; speedup vs baseline: 2.4816x; 2.4816x over previous
//
#include <hip/hip_runtime.h>
#include <hip/hip_bf16.h>

#define T_TOK 8192
#define DDIM  1024
#define NEXP  8
#define NT    16   // K-tiles of 64

typedef __attribute__((ext_vector_type(8))) short bf16x8;
typedef __attribute__((ext_vector_type(4))) float f32x4;

__device__ inline unsigned short f2bf(float f) {
  union { float f; unsigned int u; } a; a.f = f;
  unsigned int u = a.u;
  unsigned int r = (u + 0x7fffu + ((u >> 16) & 1u)) >> 16;  // RNE
  return (unsigned short)r;
}

__device__ inline float bf2f(unsigned short u) {
  union { unsigned int u; float f; } a; a.u = ((unsigned int)u) << 16;
  return a.f;
}

__device__ inline void gload_lds16(const void* g, void* l) {
  __builtin_amdgcn_global_load_lds(
      (const __attribute__((address_space(1))) void*)g,
      (__attribute__((address_space(3))) void*)l, 16, 0, 0);
}

// ---------------- cast f32 -> bf16 (expert weights) ----------------
__global__ __launch_bounds__(256) void cast_bf16_kernel(
    const float* __restrict__ in, unsigned short* __restrict__ out, int n4) {
  int i = blockIdx.x * 256 + threadIdx.x;
  if (i >= n4) return;
  float4 v = reinterpret_cast<const float4*>(in)[i];
  ushort4 o;
  o.x = f2bf(v.x); o.y = f2bf(v.y); o.z = f2bf(v.z); o.w = f2bf(v.w);
  reinterpret_cast<ushort4*>(out)[i] = o;
}

// ---------------- gating (fused x->bf16 cast), NO global atomics ----------------
__global__ __launch_bounds__(256) void gate_kernel(
    const float* __restrict__ x, const float* __restrict__ gw,
    unsigned short* __restrict__ xb,
    int* __restrict__ e_of, float* __restrict__ w_of) {
  int t = blockIdx.x * 4 + (threadIdx.x >> 6);
  int lane = threadIdx.x & 63;
  const float4* xr = reinterpret_cast<const float4*>(x + (size_t)t * DDIM);
  ushort4* xbr = reinterpret_cast<ushort4*>(xb + (size_t)t * DDIM);
  float acc[NEXP];
#pragma unroll
  for (int e = 0; e < NEXP; ++e) acc[e] = 0.f;
#pragma unroll
  for (int c = 0; c < 4; ++c) {
    float4 xv = xr[c * 64 + lane];
    ushort4 o;
    o.x = f2bf(xv.x); o.y = f2bf(xv.y); o.z = f2bf(xv.z); o.w = f2bf(xv.w);
    xbr[c * 64 + lane] = o;
#pragma unroll
    for (int e = 0; e < NEXP; ++e) {
      float4 g = reinterpret_cast<const float4*>(gw + e * DDIM)[c * 64 + lane];
      acc[e] += xv.x * g.x + xv.y * g.y + xv.z * g.z + xv.w * g.w;
    }
  }
#pragma unroll
  for (int e = 0; e < NEXP; ++e) {
#pragma unroll
    for (int s = 32; s > 0; s >>= 1) acc[e] += __shfl_xor(acc[e], s);
  }
  if (lane == 0) {
    int e0 = 0; float v0 = acc[0];
#pragma unroll
    for (int e = 1; e < NEXP; ++e) if (acc[e] > v0) { v0 = acc[e]; e0 = e; }
    int e1 = (e0 == 0) ? 1 : 0; float v1 = acc[e1];
#pragma unroll
    for (int e = 0; e < NEXP; ++e)
      if (e != e0 && acc[e] > v1) { v1 = acc[e]; e1 = e; }
    float w1 = 1.f / (1.f + expf(v0 - v1));
    float w0 = 1.f - w1;
    e_of[2 * t] = e0; e_of[2 * t + 1] = e1;
    w_of[2 * t] = w0; w_of[2 * t + 1] = w1;
  }
}

// ---------------- counts: LDS histogram, 8 global atomics per block ----------------
__global__ __launch_bounds__(512) void count_kernel(
    const int* __restrict__ e_of, int* __restrict__ counts) {
  __shared__ int lc[NEXP];
  int tid = threadIdx.x;
  if (tid < NEXP) lc[tid] = 0;
  __syncthreads();
  atomicAdd(&lc[e_of[blockIdx.x * 512 + tid]], 1);
  __syncthreads();
  if (tid < NEXP) atomicAdd(&counts[tid], lc[tid]);
}

// ---------------- scan + block map ----------------
__global__ void scan_kernel(const int* __restrict__ counts,
                            int* __restrict__ offs, int* __restrict__ cursor,
                            int* __restrict__ nblk, int* __restrict__ blkmap) {
  if (threadIdx.x == 0) {
    int s = 0;
    for (int e = 0; e < NEXP; ++e) { offs[e] = s; cursor[e] = s; s += counts[e]; }
    int nb = 0;
    for (int e = 0; e < NEXP; ++e) {
      int mb = (counts[e] + 255) >> 8;
      for (int j = 0; j < mb; ++j) blkmap[nb++] = (e << 8) | j;
    }
    nblk[0] = nb;
  }
}

// ---------------- build row lists: block-aggregated cursor atomics ----------------
__global__ __launch_bounds__(256) void build_kernel(
    const int* __restrict__ e_of, int* __restrict__ cursor,
    int* __restrict__ row_src, int* __restrict__ tok_row) {
  __shared__ int lc[NEXP];
  __shared__ int lbase[NEXP];
  int tid = threadIdx.x;
  if (tid < NEXP) lc[tid] = 0;
  __syncthreads();
  int i0 = blockIdx.x * 512 + tid;
  int i1 = i0 + 256;
  int ea = e_of[i0], eb = e_of[i1];
  int ra = atomicAdd(&lc[ea], 1);
  int rb = atomicAdd(&lc[eb], 1);
  __syncthreads();
  if (tid < NEXP) lbase[tid] = atomicAdd(&cursor[tid], lc[tid]);
  __syncthreads();
  int pa = lbase[ea] + ra;
  int pb = lbase[eb] + rb;
  row_src[pa] = i0 >> 1;
  tok_row[i0] = pa;
  row_src[pb] = i1 >> 1;
  tok_row[i1] = pb;
}

// ---------------- grouped GEMM: 256x128 tile, BK=64, 8 waves (4Mx2N) ------------
// 3-buffer LDS ring, counted vmcnt(6) gate (never 0 in main loop), single
// compute instance with runtime ring pointers (R3-proven no-spill pattern).
// LDS swizzle: (row, k) -> row*64 + (((k>>3) ^ (row&7))<<3) + (k&7); staged via
// linear global_load_lds dest + pre-permuted per-lane global source.
__global__ __launch_bounds__(512, 2) void gemm_kernel(
    const unsigned short* __restrict__ xb, const unsigned short* __restrict__ Wb,
    const int* __restrict__ row_src, const int* __restrict__ counts,
    const int* __restrict__ offs, const int* __restrict__ nblk,
    const int* __restrict__ blkmap, unsigned short* __restrict__ Yb) {
  // bijective XCD swizzle: 568 = 8 * 71; 8 consecutive wg (one m-panel's
  // n-blocks) land on one XCD -> A-panel + W-panel L2 reuse.
  int orig = blockIdx.x;
  int wg = (orig & 7) * 71 + (orig >> 3);
  int mi = wg >> 3, ni = wg & 7;
  if (mi >= nblk[0]) return;
  int em = blkmap[mi];
  int e = em >> 8, mj = em & 255;
  int ce = counts[e];
  int base = offs[e];
  int m0 = mj << 8;    // 256-row m-block
  int n0 = ni << 7;    // 128-col n-block

  __shared__ unsigned short As[3][256 * 64];  // 96 KB
  __shared__ unsigned short Bs[3][128 * 64];  // 48 KB

  int tid = threadIdx.x;
  int lane = tid & 63;
  int wid = tid >> 6;          // 0..7
  int wr = wid >> 1, wc = wid & 1;   // 4(M) x 2(N)

  // staging: A chunks g = wid*4+j (8 rows each, 32 chunks); B chunks wid*2+j (16)
  int rl = lane >> 3, sl = lane & 7;
  int cperm = (sl ^ rl) * 8;   // pre-swizzled global element offset
  const unsigned short* We = Wb + (size_t)e * DDIM * DDIM;
  const unsigned short* asrc[4];
  const unsigned short* bsrc[2];
#pragma unroll
  for (int j = 0; j < 4; ++j) {
    int row = (wid * 4 + j) * 8 + rl;      // [0,256)
    int i = m0 + row; if (i > ce - 1) i = ce - 1;
    int tk = row_src[base + i];
    asrc[j] = xb + (size_t)tk * DDIM + cperm;
  }
#pragma unroll
  for (int j = 0; j < 2; ++j) {
    int row = (wid * 2 + j) * 8 + rl;      // [0,128)
    bsrc[j] = We + (size_t)(n0 + row) * DDIM + cperm;
  }

  f32x4 acc[4][4];
#pragma unroll
  for (int m = 0; m < 4; ++m)
#pragma unroll
    for (int n = 0; n < 4; ++n) acc[m][n] = (f32x4){0.f, 0.f, 0.f, 0.f};

  int frow_a = wr * 64 + (lane & 15);
  int frow_b = wc * 64 + (lane & 15);
  int fchunk = lane >> 4;            // 0..3

  // prologue: stage tiles 0 -> buf0, 1 -> buf1 (6 loads each)
#pragma unroll
  for (int tt = 0; tt < 2; ++tt) {
    int koff = tt * 64;
#pragma unroll
    for (int j = 0; j < 4; ++j)
      gload_lds16(asrc[j] + koff, &As[tt][(wid * 4 + j) * 512]);
#pragma unroll
    for (int j = 0; j < 2; ++j)
      gload_lds16(bsrc[j] + koff, &Bs[tt][(wid * 2 + j) * 512]);
  }

  int bc = 0, bs = 2;   // compute buf, stage buf
  for (int t = 0; t < NT; ++t) {
    // gate: tile t's 6 loads retired; tile t+1's 6 stay in flight
    if (t < NT - 1) asm volatile("s_waitcnt vmcnt(6)" ::: "memory");
    else            asm volatile("s_waitcnt vmcnt(0)" ::: "memory");
    __builtin_amdgcn_s_barrier();
    asm volatile("" ::: "memory");

    // issue tile t+2's loads into ring slot bs (read last at iter t-1)
    if (t + 2 < NT) {
      int koff = (t + 2) * 64;
      unsigned short* Ad = &As[bs][0];
      unsigned short* Bd = &Bs[bs][0];
#pragma unroll
      for (int j = 0; j < 4; ++j)
        gload_lds16(asrc[j] + koff, Ad + (wid * 4 + j) * 512);
#pragma unroll
      for (int j = 0; j < 2; ++j)
        gload_lds16(bsrc[j] + koff, Bd + (wid * 2 + j) * 512);
    }

    const unsigned short* Ar = &As[bc][0];
    const unsigned short* Br = &Bs[bc][0];
#pragma unroll
    for (int ks = 0; ks < 2; ++ks) {
      int c = fchunk + ks * 4;
      bf16x8 af[4], bfr[4];
#pragma unroll
      for (int m = 0; m < 4; ++m) {
        int row = frow_a + m * 16;
        af[m] = *reinterpret_cast<const bf16x8*>(
            &Ar[row * 64 + ((c ^ (row & 7)) << 3)]);
      }
#pragma unroll
      for (int n = 0; n < 4; ++n) {
        int row = frow_b + n * 16;
        bfr[n] = *reinterpret_cast<const bf16x8*>(
            &Br[row * 64 + ((c ^ (row & 7)) << 3)]);
      }
      __builtin_amdgcn_s_setprio(1);
#pragma unroll
      for (int m = 0; m < 4; ++m)
#pragma unroll
        for (int n = 0; n < 4; ++n)
          acc[m][n] = __builtin_amdgcn_mfma_f32_16x16x32_bf16(af[m], bfr[n], acc[m][n], 0, 0, 0);
      __builtin_amdgcn_s_setprio(0);
    }
    bc = (bc == 2) ? 0 : bc + 1;
    bs = (bs == 2) ? 0 : bs + 1;
  }

  // epilogue: C/D layout col=lane&15, row=(lane>>4)*4+reg
  int crow = (lane >> 4) * 4;
  int ccol = lane & 15;
#pragma unroll
  for (int m = 0; m < 4; ++m) {
#pragma unroll
    for (int r = 0; r < 4; ++r) {
      int grow = m0 + wr * 64 + m * 16 + crow + r;
      if (grow < ce) {
        unsigned short* yr = Yb + (size_t)(base + grow) * DDIM + n0 + wc * 64 + ccol;
#pragma unroll
        for (int n = 0; n < 4; ++n)
          yr[n * 16] = f2bf(acc[m][n][r]);
      }
    }
  }
}

// ---------------- combine: out[t] = w0*Y[p0] + w1*Y[p1] ----------------
__global__ __launch_bounds__(256) void combine_kernel(
    const unsigned short* __restrict__ Yb, const int* __restrict__ tok_row,
    const float* __restrict__ w_of, float* __restrict__ out) {
  int t = blockIdx.x;
  int d = threadIdx.x * 4;
  int p0 = tok_row[2 * t], p1 = tok_row[2 * t + 1];
  float w0 = w_of[2 * t], w1 = w_of[2 * t + 1];
  ushort4 y0 = reinterpret_cast<const ushort4*>(Yb + (size_t)p0 * DDIM + d)[0];
  ushort4 y1 = reinterpret_cast<const ushort4*>(Yb + (size_t)p1 * DDIM + d)[0];
  float4 o;
  o.x = w0 * bf2f(y0.x) + w1 * bf2f(y1.x);
  o.y = w0 * bf2f(y0.y) + w1 * bf2f(y1.y);
  o.z = w0 * bf2f(y0.z) + w1 * bf2f(y1.z);
  o.w = w0 * bf2f(y0.w) + w1 * bf2f(y1.w);
  reinterpret_cast<float4*>(out + (size_t)t * DDIM + d)[0] = o;
}

extern "C" void kernel_launch(void* const* d_in, const int* in_sizes, int n_in,
                              void* d_out, int out_size, void* d_ws, size_t ws_size,
                              hipStream_t stream) {
  const float* x  = (const float*)d_in[0];
  const float* gw = (const float*)d_in[1];
  const float* ew = (const float*)d_in[2];
  float* out = (float*)d_out;
  char* ws = (char*)d_ws;

  unsigned short* xb = (unsigned short*)(ws);                    // 16 MB
  unsigned short* Wb = (unsigned short*)(ws + 16777216);         // 16 MB
  unsigned short* Yb = (unsigned short*)(ws + 33554432);         // 32 MB
  int*   e_of    = (int*)  (ws + 67108864);
  float* w_of    = (float*)(ws + 67174400);
  int*   row_src = (int*)  (ws + 67239936);
  int*   tok_row = (int*)  (ws + 67305472);
  int*   counts  = (int*)  (ws + 67371008);
  int*   offs    = (int*)  (ws + 67371040);
  int*   cursor  = (int*)  (ws + 67371072);
  int*   nblk    = (int*)  (ws + 67371104);
  int*   blkmap  = (int*)  (ws + 67371136);

  hipMemsetAsync(counts, 0, 32, stream);

  int n4w = (NEXP * DDIM * DDIM) / 4;
  cast_bf16_kernel<<<n4w / 256, 256, 0, stream>>>(ew, Wb, n4w);

  gate_kernel<<<T_TOK / 4, 256, 0, stream>>>(x, gw, xb, e_of, w_of);
  count_kernel<<<32, 512, 0, stream>>>(e_of, counts);
  scan_kernel<<<1, 64, 0, stream>>>(counts, offs, cursor, nblk, blkmap);
  build_kernel<<<32, 256, 0, stream>>>(e_of, cursor, row_src, tok_row);

  gemm_kernel<<<568, 512, 0, stream>>>(xb, Wb, row_src, counts, offs, nblk, blkmap, Yb);

  combine_kernel<<<T_TOK, 256, 0, stream>>>(Yb, tok_row, w_of, out);
}

// Round 6
// 106.077 us; speedup vs baseline: 2.7672x; 1.1151x over previous
//
#include <hip/hip_runtime.h>
#include <hip/hip_bf16.h>

#define T_TOK 8192
#define DDIM  1024
#define NEXP  8
#define NT    16   // K-tiles of 64

typedef __attribute__((ext_vector_type(8))) short bf16x8;
typedef __attribute__((ext_vector_type(4))) float f32x4;

__device__ inline unsigned short f2bf(float f) {
  union { float f; unsigned int u; } a; a.f = f;
  unsigned int u = a.u;
  unsigned int r = (u + 0x7fffu + ((u >> 16) & 1u)) >> 16;  // RNE
  return (unsigned short)r;
}

__device__ inline float bf2f(unsigned short u) {
  union { unsigned int u; float f; } a; a.u = ((unsigned int)u) << 16;
  return a.f;
}

__device__ inline void gload_lds16(const void* g, void* l) {
  __builtin_amdgcn_global_load_lds(
      (const __attribute__((address_space(1))) void*)g,
      (__attribute__((address_space(3))) void*)l, 16, 0, 0);
}

// ---------------- fused prep: blocks [0,2048) gate+cast-x, [2048,10240) cast W --
__global__ __launch_bounds__(256) void prep_kernel(
    const float* __restrict__ x, const float* __restrict__ gw,
    const float* __restrict__ ew,
    unsigned short* __restrict__ xb, unsigned short* __restrict__ Wb,
    int* __restrict__ e_of, float* __restrict__ w_of) {
  if (blockIdx.x >= 2048) {
    // cast expert weights f32 -> bf16, float4 at a time
    int i = (blockIdx.x - 2048) * 256 + threadIdx.x;   // < 2097152
    float4 v = reinterpret_cast<const float4*>(ew)[i];
    ushort4 o;
    o.x = f2bf(v.x); o.y = f2bf(v.y); o.z = f2bf(v.z); o.w = f2bf(v.w);
    reinterpret_cast<ushort4*>(Wb)[i] = o;
    return;
  }
  int t = blockIdx.x * 4 + (threadIdx.x >> 6);
  int lane = threadIdx.x & 63;
  const float4* xr = reinterpret_cast<const float4*>(x + (size_t)t * DDIM);
  ushort4* xbr = reinterpret_cast<ushort4*>(xb + (size_t)t * DDIM);
  float acc[NEXP];
#pragma unroll
  for (int e = 0; e < NEXP; ++e) acc[e] = 0.f;
#pragma unroll
  for (int c = 0; c < 4; ++c) {
    float4 xv = xr[c * 64 + lane];
    ushort4 o;
    o.x = f2bf(xv.x); o.y = f2bf(xv.y); o.z = f2bf(xv.z); o.w = f2bf(xv.w);
    xbr[c * 64 + lane] = o;
#pragma unroll
    for (int e = 0; e < NEXP; ++e) {
      float4 g = reinterpret_cast<const float4*>(gw + e * DDIM)[c * 64 + lane];
      acc[e] += xv.x * g.x + xv.y * g.y + xv.z * g.z + xv.w * g.w;
    }
  }
#pragma unroll
  for (int e = 0; e < NEXP; ++e) {
#pragma unroll
    for (int s = 32; s > 0; s >>= 1) acc[e] += __shfl_xor(acc[e], s);
  }
  if (lane == 0) {
    int e0 = 0; float v0 = acc[0];
#pragma unroll
    for (int e = 1; e < NEXP; ++e) if (acc[e] > v0) { v0 = acc[e]; e0 = e; }
    int e1 = (e0 == 0) ? 1 : 0; float v1 = acc[e1];
#pragma unroll
    for (int e = 0; e < NEXP; ++e)
      if (e != e0 && acc[e] > v1) { v1 = acc[e]; e1 = e; }
    float w1 = 1.f / (1.f + expf(v0 - v1));
    float w0 = 1.f - w1;
    e_of[2 * t] = e0; e_of[2 * t + 1] = e1;
    w_of[2 * t] = w0; w_of[2 * t + 1] = w1;
  }
}

// ---------------- counts: LDS histogram, 8 global atomics per block ----------------
__global__ __launch_bounds__(512) void count_kernel(
    const int* __restrict__ e_of, int* __restrict__ counts) {
  __shared__ int lc[NEXP];
  int tid = threadIdx.x;
  if (tid < NEXP) lc[tid] = 0;
  __syncthreads();
  atomicAdd(&lc[e_of[blockIdx.x * 512 + tid]], 1);
  __syncthreads();
  if (tid < NEXP) atomicAdd(&counts[tid], lc[tid]);
}

// ---------------- scan + block map (BM = 128) ----------------
__global__ void scan_kernel(const int* __restrict__ counts,
                            int* __restrict__ offs, int* __restrict__ cursor,
                            int* __restrict__ nblk, int* __restrict__ blkmap) {
  if (threadIdx.x == 0) {
    int s = 0;
    for (int e = 0; e < NEXP; ++e) { offs[e] = s; cursor[e] = s; s += counts[e]; }
    int nb = 0;
    for (int e = 0; e < NEXP; ++e) {
      int mb = (counts[e] + 127) >> 7;
      for (int j = 0; j < mb; ++j) blkmap[nb++] = (e << 8) | j;
    }
    nblk[0] = nb;
  }
}

// ---------------- build row lists: block-aggregated cursor atomics ----------------
__global__ __launch_bounds__(256) void build_kernel(
    const int* __restrict__ e_of, int* __restrict__ cursor,
    int* __restrict__ row_src, int* __restrict__ tok_row) {
  __shared__ int lc[NEXP];
  __shared__ int lbase[NEXP];
  int tid = threadIdx.x;
  if (tid < NEXP) lc[tid] = 0;
  __syncthreads();
  int i0 = blockIdx.x * 512 + tid;
  int i1 = i0 + 256;
  int ea = e_of[i0], eb = e_of[i1];
  int ra = atomicAdd(&lc[ea], 1);
  int rb = atomicAdd(&lc[eb], 1);
  __syncthreads();
  if (tid < NEXP) lbase[tid] = atomicAdd(&cursor[tid], lc[tid]);
  __syncthreads();
  int pa = lbase[ea] + ra;
  int pb = lbase[eb] + rb;
  row_src[pa] = i0 >> 1;
  tok_row[i0] = pa;
  row_src[pb] = i1 >> 1;
  tok_row[i1] = pb;
}

// ---------------- grouped GEMM: 128x128 tile, BK=64, 4 waves (2Mx2N) ------------
// Double-buffered LDS (64 KB total -> 2 independent blocks/CU: asynchronous
// barriers fill each other's bubbles, m97 mechanism). Counted vmcnt(8) gate —
// next tile's 8 loads stay in flight across barriers; vmcnt(0) only at t=NT-1.
// LDS swizzle: (row, k) -> row*64 + (((k>>3) ^ (row&7))<<3) + (k&7); staged via
// linear global_load_lds dest + pre-permuted per-lane global source (proven 0-conflict).
__global__ __launch_bounds__(256, 2) void gemm_kernel(
    const unsigned short* __restrict__ xb, const unsigned short* __restrict__ Wb,
    const int* __restrict__ row_src, const int* __restrict__ counts,
    const int* __restrict__ offs, const int* __restrict__ nblk,
    const int* __restrict__ blkmap, unsigned short* __restrict__ Yb) {
  // bijective XCD swizzle: 1080 = 8 * 135; consecutive wg share one XCD's L2.
  int orig = blockIdx.x;
  int wg = (orig & 7) * 135 + (orig >> 3);
  int mi = wg >> 3, ni = wg & 7;
  if (mi >= nblk[0]) return;
  int em = blkmap[mi];
  int e = em >> 8, mj = em & 255;
  int ce = counts[e];
  int base = offs[e];
  int m0 = mj << 7;    // 128-row m-block
  int n0 = ni << 7;    // 128-col n-block

  __shared__ unsigned short As[2][128 * 64];  // 32 KB
  __shared__ unsigned short Bs[2][128 * 64];  // 32 KB

  int tid = threadIdx.x;
  int lane = tid & 63;
  int wid = tid >> 6;          // 0..3
  int wr = wid >> 1, wc = wid & 1;   // 2(M) x 2(N), wave tile 64x64

  // staging: wave wid owns chunks g = wid*4+j (8 rows each) for A and B
  int rl = lane >> 3, sl = lane & 7;
  int cperm = (sl ^ rl) * 8;   // pre-swizzled global element offset
  const unsigned short* We = Wb + (size_t)e * DDIM * DDIM;
  const unsigned short* asrc[4];
  const unsigned short* bsrc[4];
#pragma unroll
  for (int j = 0; j < 4; ++j) {
    int row = (wid * 4 + j) * 8 + rl;      // [0,128)
    int i = m0 + row; if (i > ce - 1) i = ce - 1;
    int tk = row_src[base + i];
    asrc[j] = xb + (size_t)tk * DDIM + cperm;
    bsrc[j] = We + (size_t)(n0 + row) * DDIM + cperm;
  }

  f32x4 acc[4][4];
#pragma unroll
  for (int m = 0; m < 4; ++m)
#pragma unroll
    for (int n = 0; n < 4; ++n) acc[m][n] = (f32x4){0.f, 0.f, 0.f, 0.f};

  int frow_a = wr * 64 + (lane & 15);
  int frow_b = wc * 64 + (lane & 15);
  int fchunk = lane >> 4;            // 0..3

  // prologue: stage tile 0 -> buf0 (8 loads/wave)
#pragma unroll
  for (int j = 0; j < 4; ++j)
    gload_lds16(asrc[j], &As[0][(wid * 4 + j) * 512]);
#pragma unroll
  for (int j = 0; j < 4; ++j)
    gload_lds16(bsrc[j], &Bs[0][(wid * 4 + j) * 512]);

  for (int t = 0; t < NT; ++t) {
    int b = t & 1;
    if (t + 1 < NT) {
      // issue tile t+1's loads into the other buffer (last read at iter t-1,
      // protected by the end-of-iter barrier), THEN gate on tile t.
      int koff = (t + 1) * 64;
      unsigned short* Ad = &As[b ^ 1][0];
      unsigned short* Bd = &Bs[b ^ 1][0];
#pragma unroll
      for (int j = 0; j < 4; ++j)
        gload_lds16(asrc[j] + koff, Ad + (wid * 4 + j) * 512);
#pragma unroll
      for (int j = 0; j < 4; ++j)
        gload_lds16(bsrc[j] + koff, Bd + (wid * 4 + j) * 512);
      asm volatile("s_waitcnt vmcnt(8)" ::: "memory");  // tile t landed
    } else {
      asm volatile("s_waitcnt vmcnt(0)" ::: "memory");  // final drain
    }
    __builtin_amdgcn_s_barrier();
    asm volatile("" ::: "memory");

    const unsigned short* Ar = &As[b][0];
    const unsigned short* Br = &Bs[b][0];
#pragma unroll
    for (int ks = 0; ks < 2; ++ks) {
      int c = fchunk + ks * 4;
      bf16x8 af[4], bfr[4];
#pragma unroll
      for (int m = 0; m < 4; ++m) {
        int row = frow_a + m * 16;
        af[m] = *reinterpret_cast<const bf16x8*>(
            &Ar[row * 64 + ((c ^ (row & 7)) << 3)]);
      }
#pragma unroll
      for (int n = 0; n < 4; ++n) {
        int row = frow_b + n * 16;
        bfr[n] = *reinterpret_cast<const bf16x8*>(
            &Br[row * 64 + ((c ^ (row & 7)) << 3)]);
      }
      __builtin_amdgcn_s_setprio(1);
#pragma unroll
      for (int m = 0; m < 4; ++m)
#pragma unroll
        for (int n = 0; n < 4; ++n)
          acc[m][n] = __builtin_amdgcn_mfma_f32_16x16x32_bf16(af[m], bfr[n], acc[m][n], 0, 0, 0);
      __builtin_amdgcn_s_setprio(0);
    }
    asm volatile("" ::: "memory");
    __builtin_amdgcn_s_barrier();   // all waves done reading buf b
  }

  // epilogue: C/D layout col=lane&15, row=(lane>>4)*4+reg
  int crow = (lane >> 4) * 4;
  int ccol = lane & 15;
#pragma unroll
  for (int m = 0; m < 4; ++m) {
#pragma unroll
    for (int r = 0; r < 4; ++r) {
      int grow = m0 + wr * 64 + m * 16 + crow + r;
      if (grow < ce) {
        unsigned short* yr = Yb + (size_t)(base + grow) * DDIM + n0 + wc * 64 + ccol;
#pragma unroll
        for (int n = 0; n < 4; ++n)
          yr[n * 16] = f2bf(acc[m][n][r]);
      }
    }
  }
}

// ---------------- combine: out[t] = w0*Y[p0] + w1*Y[p1] ----------------
__global__ __launch_bounds__(256) void combine_kernel(
    const unsigned short* __restrict__ Yb, const int* __restrict__ tok_row,
    const float* __restrict__ w_of, float* __restrict__ out) {
  int t = blockIdx.x;
  int d = threadIdx.x * 4;
  int p0 = tok_row[2 * t], p1 = tok_row[2 * t + 1];
  float w0 = w_of[2 * t], w1 = w_of[2 * t + 1];
  ushort4 y0 = reinterpret_cast<const ushort4*>(Yb + (size_t)p0 * DDIM + d)[0];
  ushort4 y1 = reinterpret_cast<const ushort4*>(Yb + (size_t)p1 * DDIM + d)[0];
  float4 o;
  o.x = w0 * bf2f(y0.x) + w1 * bf2f(y1.x);
  o.y = w0 * bf2f(y0.y) + w1 * bf2f(y1.y);
  o.z = w0 * bf2f(y0.z) + w1 * bf2f(y1.z);
  o.w = w0 * bf2f(y0.w) + w1 * bf2f(y1.w);
  reinterpret_cast<float4*>(out + (size_t)t * DDIM + d)[0] = o;
}

extern "C" void kernel_launch(void* const* d_in, const int* in_sizes, int n_in,
                              void* d_out, int out_size, void* d_ws, size_t ws_size,
                              hipStream_t stream) {
  const float* x  = (const float*)d_in[0];
  const float* gw = (const float*)d_in[1];
  const float* ew = (const float*)d_in[2];
  float* out = (float*)d_out;
  char* ws = (char*)d_ws;

  unsigned short* xb = (unsigned short*)(ws);                    // 16 MB
  unsigned short* Wb = (unsigned short*)(ws + 16777216);         // 16 MB
  unsigned short* Yb = (unsigned short*)(ws + 33554432);         // 32 MB
  int*   e_of    = (int*)  (ws + 67108864);
  float* w_of    = (float*)(ws + 67174400);
  int*   row_src = (int*)  (ws + 67239936);
  int*   tok_row = (int*)  (ws + 67305472);
  int*   counts  = (int*)  (ws + 67371008);
  int*   offs    = (int*)  (ws + 67371040);
  int*   cursor  = (int*)  (ws + 67371072);
  int*   nblk    = (int*)  (ws + 67371104);
  int*   blkmap  = (int*)  (ws + 67371264);

  hipMemsetAsync(counts, 0, 32, stream);

  prep_kernel<<<10240, 256, 0, stream>>>(x, gw, ew, xb, Wb, e_of, w_of);
  count_kernel<<<32, 512, 0, stream>>>(e_of, counts);
  scan_kernel<<<1, 64, 0, stream>>>(counts, offs, cursor, nblk, blkmap);
  build_kernel<<<32, 256, 0, stream>>>(e_of, cursor, row_src, tok_row);

  gemm_kernel<<<1080, 256, 0, stream>>>(xb, Wb, row_src, counts, offs, nblk, blkmap, Yb);

  combine_kernel<<<T_TOK, 256, 0, stream>>>(Yb, tok_row, w_of, out);
}

// Round 7
// 96.103 us; speedup vs baseline: 3.0544x; 1.1038x over previous
//
#include <hip/hip_runtime.h>
#include <hip/hip_bf16.h>

#define T_TOK 8192
#define DDIM  1024
#define NEXP  8
#define NT    16   // K-tiles of 64

typedef __attribute__((ext_vector_type(8))) short bf16x8;
typedef __attribute__((ext_vector_type(4))) float f32x4;

__device__ inline unsigned short f2bf(float f) {
  union { float f; unsigned int u; } a; a.f = f;
  unsigned int u = a.u;
  unsigned int r = (u + 0x7fffu + ((u >> 16) & 1u)) >> 16;  // RNE
  return (unsigned short)r;
}

__device__ inline float bf2f(unsigned short u) {
  union { unsigned int u; float f; } a; a.u = ((unsigned int)u) << 16;
  return a.f;
}

__device__ inline void gload_lds16(const void* g, void* l) {
  __builtin_amdgcn_global_load_lds(
      (const __attribute__((address_space(1))) void*)g,
      (__attribute__((address_space(3))) void*)l, 16, 0, 0);
}

// ---------------- fused prep: blocks [0,2048) gate+cast-x, [2048,10240) cast W --
__global__ __launch_bounds__(256) void prep_kernel(
    const float* __restrict__ x, const float* __restrict__ gw,
    const float* __restrict__ ew,
    unsigned short* __restrict__ xb, unsigned short* __restrict__ Wb,
    int* __restrict__ e_of, float* __restrict__ w_of) {
  if (blockIdx.x >= 2048) {
    int i = (blockIdx.x - 2048) * 256 + threadIdx.x;   // < 2097152
    float4 v = reinterpret_cast<const float4*>(ew)[i];
    ushort4 o;
    o.x = f2bf(v.x); o.y = f2bf(v.y); o.z = f2bf(v.z); o.w = f2bf(v.w);
    reinterpret_cast<ushort4*>(Wb)[i] = o;
    return;
  }
  int t = blockIdx.x * 4 + (threadIdx.x >> 6);
  int lane = threadIdx.x & 63;
  const float4* xr = reinterpret_cast<const float4*>(x + (size_t)t * DDIM);
  ushort4* xbr = reinterpret_cast<ushort4*>(xb + (size_t)t * DDIM);
  float acc[NEXP];
#pragma unroll
  for (int e = 0; e < NEXP; ++e) acc[e] = 0.f;
#pragma unroll
  for (int c = 0; c < 4; ++c) {
    float4 xv = xr[c * 64 + lane];
    ushort4 o;
    o.x = f2bf(xv.x); o.y = f2bf(xv.y); o.z = f2bf(xv.z); o.w = f2bf(xv.w);
    xbr[c * 64 + lane] = o;
#pragma unroll
    for (int e = 0; e < NEXP; ++e) {
      float4 g = reinterpret_cast<const float4*>(gw + e * DDIM)[c * 64 + lane];
      acc[e] += xv.x * g.x + xv.y * g.y + xv.z * g.z + xv.w * g.w;
    }
  }
#pragma unroll
  for (int e = 0; e < NEXP; ++e) {
#pragma unroll
    for (int s = 32; s > 0; s >>= 1) acc[e] += __shfl_xor(acc[e], s);
  }
  if (lane == 0) {
    int e0 = 0; float v0 = acc[0];
#pragma unroll
    for (int e = 1; e < NEXP; ++e) if (acc[e] > v0) { v0 = acc[e]; e0 = e; }
    int e1 = (e0 == 0) ? 1 : 0; float v1 = acc[e1];
#pragma unroll
    for (int e = 0; e < NEXP; ++e)
      if (e != e0 && acc[e] > v1) { v1 = acc[e]; e1 = e; }
    float w1 = 1.f / (1.f + expf(v0 - v1));
    float w0 = 1.f - w1;
    e_of[2 * t] = e0; e_of[2 * t + 1] = e1;
    w_of[2 * t] = w0; w_of[2 * t + 1] = w1;
  }
}

// ---------------- counts: LDS histogram, 8 global atomics per block ----------------
__global__ __launch_bounds__(512) void count_kernel(
    const int* __restrict__ e_of, int* __restrict__ counts) {
  __shared__ int lc[NEXP];
  int tid = threadIdx.x;
  if (tid < NEXP) lc[tid] = 0;
  __syncthreads();
  atomicAdd(&lc[e_of[blockIdx.x * 512 + tid]], 1);
  __syncthreads();
  if (tid < NEXP) atomicAdd(&counts[tid], lc[tid]);
}

// ---------------- scan + block map (BM = 128) ----------------
__global__ void scan_kernel(const int* __restrict__ counts,
                            int* __restrict__ offs, int* __restrict__ cursor,
                            int* __restrict__ nblk, int* __restrict__ blkmap) {
  if (threadIdx.x == 0) {
    int s = 0;
    for (int e = 0; e < NEXP; ++e) { offs[e] = s; cursor[e] = s; s += counts[e]; }
    int nb = 0;
    for (int e = 0; e < NEXP; ++e) {
      int mb = (counts[e] + 127) >> 7;
      for (int j = 0; j < mb; ++j) blkmap[nb++] = (e << 8) | j;
    }
    nblk[0] = nb;
  }
}

// ---------------- build row lists: block-aggregated cursor atomics ----------------
__global__ __launch_bounds__(256) void build_kernel(
    const int* __restrict__ e_of, int* __restrict__ cursor,
    int* __restrict__ row_src, int* __restrict__ tok_row) {
  __shared__ int lc[NEXP];
  __shared__ int lbase[NEXP];
  int tid = threadIdx.x;
  if (tid < NEXP) lc[tid] = 0;
  __syncthreads();
  int i0 = blockIdx.x * 512 + tid;
  int i1 = i0 + 256;
  int ea = e_of[i0], eb = e_of[i1];
  int ra = atomicAdd(&lc[ea], 1);
  int rb = atomicAdd(&lc[eb], 1);
  __syncthreads();
  if (tid < NEXP) lbase[tid] = atomicAdd(&cursor[tid], lc[tid]);
  __syncthreads();
  int pa = lbase[ea] + ra;
  int pb = lbase[eb] + rb;
  row_src[pa] = i0 >> 1;
  tok_row[i0] = pa;
  row_src[pb] = i1 >> 1;
  tok_row[i1] = pb;
}

// ---------------- grouped GEMM: 128x128 tile, BK=64, 4 waves (2Mx2N) ------------
// Single-buffered LDS (32 KB total) + __launch_bounds__(256,4) -> 4 independent
// blocks/CU: asynchronous per-block barriers fill each other's stage-drain
// bubbles (m97 mechanism, 874 TF dense at 3 blocks/CU).
// LDS swizzle: (row, k) -> row*64 + (((k>>3) ^ (row&7))<<3) + (k&7); staged via
// linear global_load_lds dest + pre-permuted per-lane global source (measured
// 0 bank conflicts in R5/R6).
__global__ __launch_bounds__(256, 4) void gemm_kernel(
    const unsigned short* __restrict__ xb, const unsigned short* __restrict__ Wb,
    const int* __restrict__ row_src, const int* __restrict__ counts,
    const int* __restrict__ offs, const int* __restrict__ nblk,
    const int* __restrict__ blkmap, unsigned short* __restrict__ Yb) {
  // bijective XCD swizzle: 1080 = 8 * 135; consecutive wg share one XCD's L2.
  int orig = blockIdx.x;
  int wg = (orig & 7) * 135 + (orig >> 3);
  int mi = wg >> 3, ni = wg & 7;
  if (mi >= nblk[0]) return;
  int em = blkmap[mi];
  int e = em >> 8, mj = em & 255;
  int ce = counts[e];
  int base = offs[e];
  int m0 = mj << 7;    // 128-row m-block
  int n0 = ni << 7;    // 128-col n-block

  __shared__ unsigned short As[128 * 64];  // 16 KB
  __shared__ unsigned short Bs[128 * 64];  // 16 KB

  int tid = threadIdx.x;
  int lane = tid & 63;
  int wid = tid >> 6;          // 0..3
  int wr = wid >> 1, wc = wid & 1;   // 2(M) x 2(N), wave tile 64x64

  // staging: wave wid owns chunks g = wid*4+j (8 rows each) for A and B
  int rl = lane >> 3, sl = lane & 7;
  int cperm = (sl ^ rl) * 8;   // pre-swizzled global element offset
  const unsigned short* We = Wb + (size_t)e * DDIM * DDIM;
  const unsigned short* asrc[4];
  const unsigned short* bsrc[4];
#pragma unroll
  for (int j = 0; j < 4; ++j) {
    int row = (wid * 4 + j) * 8 + rl;      // [0,128)
    int i = m0 + row; if (i > ce - 1) i = ce - 1;
    int tk = row_src[base + i];
    asrc[j] = xb + (size_t)tk * DDIM + cperm;
    bsrc[j] = We + (size_t)(n0 + row) * DDIM + cperm;
  }

  f32x4 acc[4][4];
#pragma unroll
  for (int m = 0; m < 4; ++m)
#pragma unroll
    for (int n = 0; n < 4; ++n) acc[m][n] = (f32x4){0.f, 0.f, 0.f, 0.f};

  int frow_a = wr * 64 + (lane & 15);
  int frow_b = wc * 64 + (lane & 15);
  int fchunk = lane >> 4;            // 0..3

  for (int t = 0; t < NT; ++t) {
    int koff = t * 64;
#pragma unroll
    for (int j = 0; j < 4; ++j)
      gload_lds16(asrc[j] + koff, &As[(wid * 4 + j) * 512]);
#pragma unroll
    for (int j = 0; j < 4; ++j)
      gload_lds16(bsrc[j] + koff, &Bs[(wid * 4 + j) * 512]);
    __syncthreads();   // compiler emits vmcnt(0) drain; other blocks hide it

#pragma unroll
    for (int ks = 0; ks < 2; ++ks) {
      int c = fchunk + ks * 4;
      bf16x8 af[4], bfr[4];
#pragma unroll
      for (int m = 0; m < 4; ++m) {
        int row = frow_a + m * 16;
        af[m] = *reinterpret_cast<const bf16x8*>(
            &As[row * 64 + ((c ^ (row & 7)) << 3)]);
      }
#pragma unroll
      for (int n = 0; n < 4; ++n) {
        int row = frow_b + n * 16;
        bfr[n] = *reinterpret_cast<const bf16x8*>(
            &Bs[row * 64 + ((c ^ (row & 7)) << 3)]);
      }
      __builtin_amdgcn_s_setprio(1);
#pragma unroll
      for (int m = 0; m < 4; ++m)
#pragma unroll
        for (int n = 0; n < 4; ++n)
          acc[m][n] = __builtin_amdgcn_mfma_f32_16x16x32_bf16(af[m], bfr[n], acc[m][n], 0, 0, 0);
      __builtin_amdgcn_s_setprio(0);
    }
    __syncthreads();   // all waves done reading before next stage overwrites
  }

  // epilogue: C/D layout col=lane&15, row=(lane>>4)*4+reg
  int crow = (lane >> 4) * 4;
  int ccol = lane & 15;
#pragma unroll
  for (int m = 0; m < 4; ++m) {
#pragma unroll
    for (int r = 0; r < 4; ++r) {
      int grow = m0 + wr * 64 + m * 16 + crow + r;
      if (grow < ce) {
        unsigned short* yr = Yb + (size_t)(base + grow) * DDIM + n0 + wc * 64 + ccol;
#pragma unroll
        for (int n = 0; n < 4; ++n)
          yr[n * 16] = f2bf(acc[m][n][r]);
      }
    }
  }
}

// ---------------- combine: out[t] = w0*Y[p0] + w1*Y[p1] ----------------
__global__ __launch_bounds__(256) void combine_kernel(
    const unsigned short* __restrict__ Yb, const int* __restrict__ tok_row,
    const float* __restrict__ w_of, float* __restrict__ out) {
  int t = blockIdx.x;
  int d = threadIdx.x * 4;
  int p0 = tok_row[2 * t], p1 = tok_row[2 * t + 1];
  float w0 = w_of[2 * t], w1 = w_of[2 * t + 1];
  ushort4 y0 = reinterpret_cast<const ushort4*>(Yb + (size_t)p0 * DDIM + d)[0];
  ushort4 y1 = reinterpret_cast<const ushort4*>(Yb + (size_t)p1 * DDIM + d)[0];
  float4 o;
  o.x = w0 * bf2f(y0.x) + w1 * bf2f(y1.x);
  o.y = w0 * bf2f(y0.y) + w1 * bf2f(y1.y);
  o.z = w0 * bf2f(y0.z) + w1 * bf2f(y1.z);
  o.w = w0 * bf2f(y0.w) + w1 * bf2f(y1.w);
  reinterpret_cast<float4*>(out + (size_t)t * DDIM + d)[0] = o;
}

extern "C" void kernel_launch(void* const* d_in, const int* in_sizes, int n_in,
                              void* d_out, int out_size, void* d_ws, size_t ws_size,
                              hipStream_t stream) {
  const float* x  = (const float*)d_in[0];
  const float* gw = (const float*)d_in[1];
  const float* ew = (const float*)d_in[2];
  float* out = (float*)d_out;
  char* ws = (char*)d_ws;

  unsigned short* xb = (unsigned short*)(ws);                    // 16 MB
  unsigned short* Wb = (unsigned short*)(ws + 16777216);         // 16 MB
  unsigned short* Yb = (unsigned short*)(ws + 33554432);         // 32 MB
  int*   e_of    = (int*)  (ws + 67108864);
  float* w_of    = (float*)(ws + 67174400);
  int*   row_src = (int*)  (ws + 67239936);
  int*   tok_row = (int*)  (ws + 67305472);
  int*   counts  = (int*)  (ws + 67371008);
  int*   offs    = (int*)  (ws + 67371040);
  int*   cursor  = (int*)  (ws + 67371072);
  int*   nblk    = (int*)  (ws + 67371104);
  int*   blkmap  = (int*)  (ws + 67371264);

  hipMemsetAsync(counts, 0, 32, stream);

  prep_kernel<<<10240, 256, 0, stream>>>(x, gw, ew, xb, Wb, e_of, w_of);
  count_kernel<<<32, 512, 0, stream>>>(e_of, counts);
  scan_kernel<<<1, 64, 0, stream>>>(counts, offs, cursor, nblk, blkmap);
  build_kernel<<<32, 256, 0, stream>>>(e_of, cursor, row_src, tok_row);

  gemm_kernel<<<1080, 256, 0, stream>>>(xb, Wb, row_src, counts, offs, nblk, blkmap, Yb);

  combine_kernel<<<T_TOK, 256, 0, stream>>>(Yb, tok_row, w_of, out);
}